// Round 2
// baseline (551.678 us; speedup 1.0000x reference)
//
#include <hip/hip_runtime.h>
#include <stdint.h>

// RelationalGraphletConvolution: out[b,g,f] = sum_{i,j,d} R[b,t_i,t_j,d]*filt[f,i,j,d]
// B=32, N=32, D=16, F=16, K=3, G=C(32,3)=4960. fp32 in / fp32 out (per reference dtypes).

#define NOBJ 32
#define NG   4960
#define NF   16
#define ND   16
#define GTILE 512   // 256 threads x 2 groups each

__device__ __forceinline__ void unrank3(int g, int& t0, int& t1, int& t2) {
    int rem = g;
    t0 = 0;
    for (;;) { int c = ((31 - t0) * (30 - t0)) >> 1; if (rem < c) break; rem -= c; ++t0; }
    t1 = t0 + 1;
    for (;;) { int c = 31 - t1; if (rem < c) break; rem -= c; ++t1; }
    t2 = t1 + 1 + rem;
}

__global__ __launch_bounds__(256) void rgc_kernel(
    const float* __restrict__ R,    // (32,32,32,16)
    const float* __restrict__ Fw,   // (16,3,3,16)
    float* __restrict__ out)        // (32,4960,16)
{
    // filters in LDS as float4, layout [f][ij][dv]; reads are wave-uniform -> broadcast
    __shared__ float4 sf[NF * 9 * 4];
    const float4* Fw4 = (const float4*)Fw;
    for (int i = threadIdx.x; i < NF * 9 * 4; i += 256) sf[i] = Fw4[i];
    __syncthreads();

    const int b  = blockIdx.y;
    const int g0 = blockIdx.x * GTILE + threadIdx.x;       // always < NG (10*512 grid, max 4863)
    const int g1r = g0 + 256;
    const bool has1 = (g1r < NG);
    const int g1 = has1 ? g1r : g0;                        // clamp so loads stay in-bounds

    int a0, a1, a2, b0, b1, b2;
    unrank3(g0, a0, a1, a2);
    unrank3(g1, b0, b1, b2);
    const int ta[3] = {a0, a1, a2};
    const int tb[3] = {b0, b1, b2};

    const float* Rb = R + (size_t)b * (NOBJ * NOBJ * ND);

    float acc0[NF], acc1[NF];
#pragma unroll
    for (int f = 0; f < NF; ++f) { acc0[f] = 0.f; acc1[f] = 0.f; }

#pragma unroll
    for (int i = 0; i < 3; ++i) {
#pragma unroll
        for (int j = 0; j < 3; ++j) {
            const float4* r0p = (const float4*)(Rb + (ta[i] * NOBJ + ta[j]) * ND);
            const float4* r1p = (const float4*)(Rb + (tb[i] * NOBJ + tb[j]) * ND);
            float4 r0[4], r1[4];
#pragma unroll
            for (int dv = 0; dv < 4; ++dv) { r0[dv] = r0p[dv]; r1[dv] = r1p[dv]; }
            const int ij = i * 3 + j;
#pragma unroll
            for (int f = 0; f < NF; ++f) {
                const int base = (f * 9 + ij) * 4;
                float s0 = acc0[f], s1 = acc1[f];
#pragma unroll
                for (int dv = 0; dv < 4; ++dv) {
                    const float4 w = sf[base + dv];        // uniform addr -> LDS broadcast
                    s0 = fmaf(r0[dv].x, w.x, s0);
                    s0 = fmaf(r0[dv].y, w.y, s0);
                    s0 = fmaf(r0[dv].z, w.z, s0);
                    s0 = fmaf(r0[dv].w, w.w, s0);
                    s1 = fmaf(r1[dv].x, w.x, s1);
                    s1 = fmaf(r1[dv].y, w.y, s1);
                    s1 = fmaf(r1[dv].z, w.z, s1);
                    s1 = fmaf(r1[dv].w, w.w, s1);
                }
                acc0[f] = s0; acc1[f] = s1;
            }
        }
    }

    float4* op0 = (float4*)(out + ((size_t)b * NG + g0) * NF);
#pragma unroll
    for (int v = 0; v < 4; ++v) {
        float4 o;
        o.x = acc0[v * 4 + 0]; o.y = acc0[v * 4 + 1];
        o.z = acc0[v * 4 + 2]; o.w = acc0[v * 4 + 3];
        op0[v] = o;
    }
    if (has1) {
        float4* op1 = (float4*)(out + ((size_t)b * NG + g1) * NF);
#pragma unroll
        for (int v = 0; v < 4; ++v) {
            float4 o;
            o.x = acc1[v * 4 + 0]; o.y = acc1[v * 4 + 1];
            o.z = acc1[v * 4 + 2]; o.w = acc1[v * 4 + 3];
            op1[v] = o;
        }
    }
}

extern "C" void kernel_launch(void* const* d_in, const int* in_sizes, int n_in,
                              void* d_out, int out_size, void* d_ws, size_t ws_size,
                              hipStream_t stream) {
    // defensive: identify tensors by element count (R=524288, filters=2304)
    const float* R  = (const float*)d_in[0];
    const float* Fw = (const float*)d_in[1];
    if (n_in >= 2 && in_sizes[0] == NF * 9 * ND) { R = (const float*)d_in[1]; Fw = (const float*)d_in[0]; }
    float* out = (float*)d_out;
    dim3 grid((NG + GTILE - 1) / GTILE, 32);   // 10 x 32 = 320 blocks
    rgc_kernel<<<grid, dim3(256, 1, 1), 0, stream>>>(R, Fw, out);
}

// Round 3
// 96.973 us; speedup vs baseline: 5.6890x; 5.6890x over previous
//
#include <hip/hip_runtime.h>
#include <stdint.h>

// RelationalGraphletConvolution: out[b,g,f] = sum_{i,j,d} R[b,t_i,t_j,d]*filt[f,i,j,d]
// B=32, N=32, D=16, F=16, K=3, G=C(32,3)=4960. fp32 in / fp32 out.
//
// R3 design notes:
//  - ij-loop is NOT unrolled (#pragma unroll 1): R2's full unroll hoisted ~288
//    VGPRs of global loads -> 256-VGPR cap -> ~930 MB scratch spill traffic.
//  - filters read from global with wave-uniform indices -> scalar s_load path
//    (SMEM pipe), v_fma consumes SGPR operand directly. No LDS at all.

#define NOBJ 32
#define NG   4960
#define NF   16
#define ND   16

__device__ __forceinline__ void unrank3(int g, int& t0, int& t1, int& t2) {
    int rem = g;
    t0 = 0;
    for (;;) { int c = ((31 - t0) * (30 - t0)) >> 1; if (rem < c) break; rem -= c; ++t0; }
    t1 = t0 + 1;
    for (;;) { int c = 31 - t1; if (rem < c) break; rem -= c; ++t1; }
    t2 = t1 + 1 + rem;
}

__global__ __launch_bounds__(256, 4) void rgc_kernel(
    const float* __restrict__ R,    // (32,32,32,16)
    const float* __restrict__ Fw,   // (16,3,3,16)
    float* __restrict__ out)        // (32,4960,16)
{
    const int g = blockIdx.x * 256 + threadIdx.x;
    const int b = blockIdx.y;
    if (g >= NG) return;

    int t0, t1, t2;
    unrank3(g, t0, t1, t2);

    const float* Rb = R + (size_t)b * (NOBJ * NOBJ * ND);

    float acc[NF];
#pragma unroll
    for (int f = 0; f < NF; ++f) acc[f] = 0.f;

#pragma unroll 1
    for (int ij = 0; ij < 9; ++ij) {
        const int i = ij / 3;          // ij is uniform; cheap scalar math
        const int j = ij - i * 3;
        const int ti = (i == 0) ? t0 : ((i == 1) ? t1 : t2);
        const int tj = (j == 0) ? t0 : ((j == 1) ? t1 : t2);

        const float4* rp = (const float4*)(Rb + (ti * NOBJ + tj) * ND);
        const float4 r0 = rp[0], r1 = rp[1], r2 = rp[2], r3 = rp[3];

        const float* fp = Fw + ij * ND;           // + f*144 + d below (uniform)
#pragma unroll
        for (int f = 0; f < NF; ++f) {
            const float* w = fp + f * (9 * ND);   // wave-uniform address -> s_load
            float a = acc[f];
            a = fmaf(r0.x, w[0],  a);
            a = fmaf(r0.y, w[1],  a);
            a = fmaf(r0.z, w[2],  a);
            a = fmaf(r0.w, w[3],  a);
            a = fmaf(r1.x, w[4],  a);
            a = fmaf(r1.y, w[5],  a);
            a = fmaf(r1.z, w[6],  a);
            a = fmaf(r1.w, w[7],  a);
            a = fmaf(r2.x, w[8],  a);
            a = fmaf(r2.y, w[9],  a);
            a = fmaf(r2.z, w[10], a);
            a = fmaf(r2.w, w[11], a);
            a = fmaf(r3.x, w[12], a);
            a = fmaf(r3.y, w[13], a);
            a = fmaf(r3.z, w[14], a);
            a = fmaf(r3.w, w[15], a);
            acc[f] = a;
        }
    }

    float4* op = (float4*)(out + ((size_t)b * NG + g) * NF);
#pragma unroll
    for (int v = 0; v < 4; ++v) {
        float4 o;
        o.x = acc[v * 4 + 0]; o.y = acc[v * 4 + 1];
        o.z = acc[v * 4 + 2]; o.w = acc[v * 4 + 3];
        op[v] = o;
    }
}

extern "C" void kernel_launch(void* const* d_in, const int* in_sizes, int n_in,
                              void* d_out, int out_size, void* d_ws, size_t ws_size,
                              hipStream_t stream) {
    const float* R  = (const float*)d_in[0];
    const float* Fw = (const float*)d_in[1];
    if (n_in >= 2 && in_sizes[0] == NF * 9 * ND) { R = (const float*)d_in[1]; Fw = (const float*)d_in[0]; }
    float* out = (float*)d_out;
    dim3 grid((NG + 255) / 256, 32);   // 20 x 32 = 640 blocks
    rgc_kernel<<<grid, dim3(256, 1, 1), 0, stream>>>(R, Fw, out);
}

// Round 4
// 68.179 us; speedup vs baseline: 8.0916x; 1.4223x over previous
//
#include <hip/hip_runtime.h>
#include <stdint.h>

// RelationalGraphletConvolution as gathered GEMM:
//   C[b*G+g, f] = sum_k A[g,k]*W[k,f],  k = ij*16+d (144), A row = gather of 9 R-rows.
// B=32, G=4960, F=16, D=16. bf16 MFMA (threshold 1.27 allows it; fp32 absmax was 0.125).
//
// Per block: 64 groups staged to LDS as bf16 (row stride KPAD=168 -> 2-way-max banks),
// filters staged as sW[f][k] (B^T layout, m91-verified gemm_bt fragment order),
// 4 waves x one 16x16 tile x 5 MFMA (K 144 padded to 160 with zeros both sides).

#define NOBJ 32
#define NG   4960
#define NF   16
#define ND   16
#define KPAD 168    // bf16 elems per LDS row (144 data + 24 pad; MFMA reads k<160)
#define GPB  64     // groups per block

typedef __bf16 bf16x8 __attribute__((ext_vector_type(8)));
typedef float  f32x4  __attribute__((ext_vector_type(4)));

__device__ __forceinline__ unsigned f2bf1(float x) {
    unsigned u = __float_as_uint(x);
    return (u + 0x7fffu + ((u >> 16) & 1u)) >> 16;   // RNE; inputs finite
}
__device__ __forceinline__ unsigned packbf(float lo, float hi) {
    return f2bf1(lo) | (f2bf1(hi) << 16);
}

__device__ __forceinline__ void unrank3(int g, int& t0, int& t1, int& t2) {
    int rem = g;
    t0 = 0;
    for (;;) { int c = ((31 - t0) * (30 - t0)) >> 1; if (rem < c) break; rem -= c; ++t0; }
    t1 = t0 + 1;
    for (;;) { int c = 31 - t1; if (rem < c) break; rem -= c; ++t1; }
    t2 = t1 + 1 + rem;
}

__global__ __launch_bounds__(256) void rgc_mfma(
    const float* __restrict__ R,    // (32,32,32,16)
    const float* __restrict__ Fw,   // (16,3,3,16) == W^T[f][k]
    float* __restrict__ out)        // (32,4960,16)
{
    __shared__ unsigned short sbuf[(GPB + NF) * KPAD];  // sA rows 0..63, sW rows 64..79
    unsigned short* sA = sbuf;
    unsigned short* sW = sbuf + GPB * KPAD;

    const int tid = threadIdx.x;
    const int b   = blockIdx.y;
    const int g0  = blockIdx.x * GPB;

    // 1) zero k=144..167 pad of all 80 rows (6x uint2 per row, 480 slots)
    for (int idx = tid; idx < (GPB + NF) * 6; idx += 256) {
        const int row = idx / 6, q = idx - row * 6;
        *(uint2*)&sbuf[row * KPAD + 144 + q * 4] = make_uint2(0u, 0u);
    }

    // 2) stage filters: sW[f][k] = bf16(Fw[f*144+k])  (contiguous read, 9 elems/thread)
    for (int e = tid; e < NF * 144; e += 256) {
        const int f = e / 144, k = e - f * 144;
        sW[f * KPAD + k] = (unsigned short)f2bf1(Fw[e]);
    }

    // 3) stage A: 4 threads per group, one float4 (16B) each per (i,j) row
    {
        const int gi = tid >> 2, q = tid & 3;
        const int g  = min(g0 + gi, NG - 1);       // clamp; duplicates masked at store
        int t0, t1, t2;
        unrank3(g, t0, t1, t2);
        const int t[3] = {t0, t1, t2};
        const float* Rb = R + (size_t)b * (NOBJ * NOBJ * ND);
#pragma unroll
        for (int ij = 0; ij < 9; ++ij) {
            const int i = ij / 3, j = ij - i * 3;
            const float4 v = *(const float4*)(Rb + (t[i] * NOBJ + t[j]) * ND + q * 4);
            uint2 pk;
            pk.x = packbf(v.x, v.y);
            pk.y = packbf(v.z, v.w);
            *(uint2*)&sA[gi * KPAD + ij * ND + q * 4] = pk;
        }
    }

    __syncthreads();

    // 4) MFMA: wave w -> groups [g0 + 16w, g0 + 16w + 16), all 16 filters, K=160
    const int wave = tid >> 6;
    const int lane = tid & 63;
    const int l15  = lane & 15;          // A row within tile / B row (=f) / C col (=f)
    const int quad = lane >> 4;          // k-subblock select / C row-group

    const unsigned short* aRow = sA + (wave * 16 + l15) * KPAD + quad * 8;
    const unsigned short* bRow = sW + l15 * KPAD + quad * 8;

    f32x4 acc = {0.f, 0.f, 0.f, 0.f};
#pragma unroll
    for (int s = 0; s < 5; ++s) {
        const bf16x8 af = *(const bf16x8*)(aRow + s * 32);
        const bf16x8 bf = *(const bf16x8*)(bRow + s * 32);
        acc = __builtin_amdgcn_mfma_f32_16x16x32_bf16(af, bf, acc, 0, 0, 0);
    }

    // 5) epilogue: C[row=quad*4+r][col=l15] -> out[b][g0+wave*16+row][f=l15]
    const int gbase = g0 + wave * 16 + quad * 4;
#pragma unroll
    for (int r = 0; r < 4; ++r) {
        const int g = gbase + r;
        if (g < NG) out[((size_t)b * NG + g) * NF + l15] = acc[r];
    }
}

extern "C" void kernel_launch(void* const* d_in, const int* in_sizes, int n_in,
                              void* d_out, int out_size, void* d_ws, size_t ws_size,
                              hipStream_t stream) {
    const float* R  = (const float*)d_in[0];
    const float* Fw = (const float*)d_in[1];
    if (n_in >= 2 && in_sizes[0] == NF * 9 * ND) { R = (const float*)d_in[1]; Fw = (const float*)d_in[0]; }
    float* out = (float*)d_out;
    dim3 grid((NG + GPB - 1) / GPB, 32);   // 78 x 32 = 2496 blocks
    rgc_mfma<<<grid, dim3(256, 1, 1), 0, stream>>>(R, Fw, out);
}

// Round 6
// 66.809 us; speedup vs baseline: 8.2575x; 1.0205x over previous
//
#include <hip/hip_runtime.h>
#include <stdint.h>

// RelationalGraphletConvolution as gathered GEMM with register-direct MFMA fragments.
//   C[b*G+g, f] = sum_k A[g,k]*W[k,f], k=ij*16+d (144 real, padded to 160).
// Pre-pass converts R -> bf16 (d_ws) and filters -> zero-padded bf16 W^T[16][160] (d_ws+1MB).
// Main kernel: no LDS, no barrier, no per-block conversion. A/B frags are direct 16B
// global loads (L1-resident: R slice 32KB/b, W 5KB). k>=144 tail: W pad is exact zeros,
// A row clamped to ij=8 (finite garbage * 0 = 0). Fragment/C layouts as verified in R4.
// R6 fix: W-conversion block loops (320 uint4 slots > 256 threads); R5 left f>=13
// unwritten (0xAA poison ~ 0) -> absmax 59 = full ref magnitude in those channels.

#define NOBJ 32
#define NG   4960
#define NF   16
#define ND   16
#define KP   160                      // padded K for W^T rows
#define RELEMS (32 * NOBJ * NOBJ * ND)  // 524288

typedef __bf16 bf16x8 __attribute__((ext_vector_type(8)));
typedef float  f32x4  __attribute__((ext_vector_type(4)));

__device__ __forceinline__ unsigned f2bf1(float x) {
    unsigned u = __float_as_uint(x);
    return (u + 0x7fffu + ((u >> 16) & 1u)) >> 16;   // RNE; inputs finite
}
__device__ __forceinline__ unsigned packbf(float lo, float hi) {
    return f2bf1(lo) | (f2bf1(hi) << 16);
}

__device__ __forceinline__ void unrank3(int g, int& t0, int& t1, int& t2) {
    int rem = g;
    t0 = 0;
    for (;;) { int c = ((31 - t0) * (30 - t0)) >> 1; if (rem < c) break; rem -= c; ++t0; }
    t1 = t0 + 1;
    for (;;) { int c = 31 - t1; if (rem < c) break; rem -= c; ++t1; }
    t2 = t1 + 1 + rem;
}

// grid 257 blocks: 0..255 convert R (8 elems/thread), block 256 builds padded W^T.
__global__ __launch_bounds__(256) void rgc_pre(
    const float* __restrict__ R, const float* __restrict__ Fw,
    unsigned short* __restrict__ Rbf, unsigned short* __restrict__ Wpad)
{
    const int tid = threadIdx.x;
    if (blockIdx.x < 256) {
        const int e = (blockIdx.x * 256 + tid) * 8;
        const float4* p = (const float4*)(R + e);
        const float4 v0 = p[0], v1 = p[1];
        uint4 o;
        o.x = packbf(v0.x, v0.y); o.y = packbf(v0.z, v0.w);
        o.z = packbf(v1.x, v1.y); o.w = packbf(v1.z, v1.w);
        *(uint4*)(Rbf + e) = o;
    } else {
        // 320 uint4 slots, 256 threads -> loop (R5 bug: guard without loop left f>=13 poisoned)
        for (int e = tid * 8; e < NF * KP; e += 256 * 8) {
            const int f = e / KP, k0 = e % KP;
            uint4 o = make_uint4(0u, 0u, 0u, 0u);
            if (k0 < 144) {
                const float4* p = (const float4*)(Fw + f * 144 + k0);
                const float4 v0 = p[0], v1 = p[1];
                o.x = packbf(v0.x, v0.y); o.y = packbf(v0.z, v0.w);
                o.z = packbf(v1.x, v1.y); o.w = packbf(v1.z, v1.w);
            }
            *(uint4*)(Wpad + e) = o;                // Wpad[f][k], k>=144 zeroed
        }
    }
}

__global__ __launch_bounds__(256) void rgc_main(
    const unsigned short* __restrict__ Rbf,   // bf16 bits, (32,32,32,16)
    const unsigned short* __restrict__ Wpad,  // bf16 bits, (16,160) zero-padded
    float* __restrict__ out)                  // (32,4960,16)
{
    const int tid  = threadIdx.x;
    const int wave = tid >> 6;
    const int lane = tid & 63;
    const int l15  = lane & 15;               // A row (group) / B row (=f) / C col (=f)
    const int quad = lane >> 4;               // k-subchunk / C row-group
    const int b    = blockIdx.y;
    const int gw   = blockIdx.x * 64 + wave * 16;

    const int g = min(gw + l15, NG - 1);      // clamp; stores masked below
    int t0, t1, t2;
    unrank3(g, t0, t1, t2);
    const int t[3] = {t0, t1, t2};

    // rowoff[ij] = element offset of R row (t_i, t_j) within the b-slice
    int rowoff[9];
#pragma unroll
    for (int ij = 0; ij < 9; ++ij) {
        const int i = ij / 3, j = ij % 3;     // compile-time
        rowoff[ij] = (t[i] * NOBJ + t[j]) * ND;
    }

    // A frag for (l15, quad) at K-step s covers k = s*32 + quad*8 + {0..7}
    //   -> ij = 2s + (quad>>1), d0 = (quad&1)*8   (verified layout, R4)
    const int hi = quad >> 1;
    const int d0 = (quad & 1) * 8;
    int ro[5];
    ro[0] = hi ? rowoff[1] : rowoff[0];
    ro[1] = hi ? rowoff[3] : rowoff[2];
    ro[2] = hi ? rowoff[5] : rowoff[4];
    ro[3] = hi ? rowoff[7] : rowoff[6];
    ro[4] = rowoff[8];                        // s=4,hi=1 is k>=144: W pad is 0, A value moot

    const unsigned short* Rb    = Rbf + (size_t)b * (NOBJ * NOBJ * ND);
    const unsigned short* wbase = Wpad + l15 * KP + quad * 8;

    f32x4 acc = {0.f, 0.f, 0.f, 0.f};
#pragma unroll
    for (int s = 0; s < 5; ++s) {
        const bf16x8 a = *(const bf16x8*)(Rb + ro[s] + d0);       // 16B, L1-resident
        const bf16x8 w = *(const bf16x8*)(wbase + s * 32);        // 16B, L1-resident
        acc = __builtin_amdgcn_mfma_f32_16x16x32_bf16(a, w, acc, 0, 0, 0);
    }

    // C[row=quad*4+r][col=l15] -> out[b][gw+quad*4+r][f=l15]
    const int gbase = gw + quad * 4;
#pragma unroll
    for (int r = 0; r < 4; ++r) {
        const int gg = gbase + r;
        if (gg < NG) out[((size_t)b * NG + gg) * NF + l15] = acc[r];
    }
}

extern "C" void kernel_launch(void* const* d_in, const int* in_sizes, int n_in,
                              void* d_out, int out_size, void* d_ws, size_t ws_size,
                              hipStream_t stream) {
    const float* R  = (const float*)d_in[0];
    const float* Fw = (const float*)d_in[1];
    if (n_in >= 2 && in_sizes[0] == NF * 9 * ND) { R = (const float*)d_in[1]; Fw = (const float*)d_in[0]; }
    float* out = (float*)d_out;

    unsigned short* Rbf  = (unsigned short*)d_ws;                       // 1 MB
    unsigned short* Wpad = (unsigned short*)((char*)d_ws + RELEMS * 2); // 5 KB

    rgc_pre<<<dim3(257, 1), dim3(256, 1, 1), 0, stream>>>(R, Fw, Rbf, Wpad);
    dim3 grid((NG + 63) / 64, 32);   // 78 x 32 = 2496 blocks, 4 independent waves each
    rgc_main<<<grid, dim3(256, 1, 1), 0, stream>>>(Rbf, Wpad, out);
}

// Round 8
// 64.809 us; speedup vs baseline: 8.5123x; 1.0309x over previous
//
#include <hip/hip_runtime.h>
#include <stdint.h>

// RelationalGraphletConvolution as gathered GEMM with register-direct MFMA fragments.
//   C[b*G+g, f] = sum_k A[g,k]*W[k,f], k=ij*16+d (144 real, padded to 160).
// Pre-pass: R -> bf16 (d_ws), filters -> zero-padded bf16 W^T[16][160] (R6-verified).
// Main: no LDS/barrier. R8: closed-form unrank (cbrtf seed; R7's __exp2f was a
// CUDA-ism that fails HIP device compile), 2-b inner loop reusing unrank + W-frags.

#define NOBJ 32
#define NG   4960
#define NF   16
#define ND   16
#define KP   160
#define RELEMS (32 * NOBJ * NOBJ * ND)  // 524288

typedef __bf16 bf16x8 __attribute__((ext_vector_type(8)));
typedef float  f32x4  __attribute__((ext_vector_type(4)));

__device__ __forceinline__ unsigned f2bf1(float x) {
    unsigned u = __float_as_uint(x);
    return (u + 0x7fffu + ((u >> 16) & 1u)) >> 16;   // RNE; inputs finite
}
__device__ __forceinline__ unsigned packbf(float lo, float hi) {
    return f2bf1(lo) | (f2bf1(hi) << 16);
}

__device__ __forceinline__ int C3i(int x) { return (x * (x - 1) * (x - 2)) / 6; } // x<=34
__device__ __forceinline__ int C2i(int x) { return (x * (x - 1)) >> 1; }

// Combinatorial-number-system inversion, branchless fixups (seed error tolerance ±2).
// x: unique int with C(x-1,3) < T <= C(x,3), T = 4960-g; t0 = 32-x.
// y: unique int with C(y-1,2) < T2 <= C(y,2), T2 = C(x-1,2) - (C(x,3)-T); t1 = 32-y.
__device__ __forceinline__ void unrank3_cf(int g, int& t0, int& t1, int& t2) {
    const int T = 4960 - g;                                  // [1,4960]
    int x = (int)cbrtf(6.0f * (float)T) + 1;
    x += (C3i(x) < T);
    x += (C3i(x) < T);
    x -= (C3i(x - 1) >= T);
    x -= (C3i(x - 1) >= T);
    t0 = 32 - x;
    const int rem2 = C3i(x) - T;                             // [0, C2(x-1))
    const int T2   = C2i(x - 1) - rem2;                      // [1, C2(x-1)]
    int y = (int)(sqrtf(2.0f * (float)T2) + 0.5f);
    y += (C2i(y) < T2);
    y += (C2i(y) < T2);
    y -= (C2i(y - 1) >= T2);
    y -= (C2i(y - 1) >= T2);
    t1 = 32 - y;
    t2 = t1 + 1 + (C2i(y) - T2);
}

// grid 257 blocks: 0..255 convert R (8 elems/thread), block 256 builds padded W^T.
__global__ __launch_bounds__(256) void rgc_pre(
    const float* __restrict__ R, const float* __restrict__ Fw,
    unsigned short* __restrict__ Rbf, unsigned short* __restrict__ Wpad)
{
    const int tid = threadIdx.x;
    if (blockIdx.x < 256) {
        const int e = (blockIdx.x * 256 + tid) * 8;
        const float4* p = (const float4*)(R + e);
        const float4 v0 = p[0], v1 = p[1];
        uint4 o;
        o.x = packbf(v0.x, v0.y); o.y = packbf(v0.z, v0.w);
        o.z = packbf(v1.x, v1.y); o.w = packbf(v1.z, v1.w);
        *(uint4*)(Rbf + e) = o;
    } else {
        for (int e = tid * 8; e < NF * KP; e += 256 * 8) {   // 320 slots / 256 thr
            const int f = e / KP, k0 = e % KP;
            uint4 o = make_uint4(0u, 0u, 0u, 0u);
            if (k0 < 144) {
                const float4* p = (const float4*)(Fw + f * 144 + k0);
                const float4 v0 = p[0], v1 = p[1];
                o.x = packbf(v0.x, v0.y); o.y = packbf(v0.z, v0.w);
                o.z = packbf(v1.x, v1.y); o.w = packbf(v1.z, v1.w);
            }
            *(uint4*)(Wpad + e) = o;                         // Wpad[f][k], k>=144 zeroed
        }
    }
}

__global__ __launch_bounds__(256) void rgc_main(
    const unsigned short* __restrict__ Rbf,   // bf16 bits, (32,32,32,16)
    const unsigned short* __restrict__ Wpad,  // bf16 bits, (16,160) zero-padded
    float* __restrict__ out)                  // (32,4960,16)
{
    const int tid  = threadIdx.x;
    const int wave = tid >> 6;
    const int lane = tid & 63;
    const int l15  = lane & 15;               // A row (group) / B row (=f) / C col (=f)
    const int quad = lane >> 4;               // k-subchunk / C row-group
    const int b0   = blockIdx.y * 2;
    const int gw   = blockIdx.x * 64 + wave * 16;

    const int g = min(gw + l15, NG - 1);      // clamp; stores masked below
    int t0, t1, t2;
    unrank3_cf(g, t0, t1, t2);
    const int t[3] = {t0, t1, t2};

    int rowoff[9];
#pragma unroll
    for (int ij = 0; ij < 9; ++ij) {
        const int i = ij / 3, j = ij % 3;     // compile-time
        rowoff[ij] = (t[i] * NOBJ + t[j]) * ND;
    }

    // A frag for (l15,quad) at K-step s covers k = s*32 + quad*8 + {0..7}
    //   -> ij = 2s + (quad>>1), d0 = (quad&1)*8   (R4/R6-verified layout)
    const int hi = quad >> 1;
    const int d0 = (quad & 1) * 8;
    int ro[5];
    ro[0] = hi ? rowoff[1] : rowoff[0];
    ro[1] = hi ? rowoff[3] : rowoff[2];
    ro[2] = hi ? rowoff[5] : rowoff[4];
    ro[3] = hi ? rowoff[7] : rowoff[6];
    ro[4] = rowoff[8];                        // s=4,hi=1 is k>=144: W pad is 0

    // W fragments once, reused across the b-loop (5 x 4 VGPRs)
    const unsigned short* wbase = Wpad + l15 * KP + quad * 8;
    bf16x8 wf[5];
#pragma unroll
    for (int s = 0; s < 5; ++s) wf[s] = *(const bf16x8*)(wbase + s * 32);

    const int gbase = gw + quad * 4;
#pragma unroll
    for (int bb = 0; bb < 2; ++bb) {
        const int b = b0 + bb;
        const unsigned short* Rb = Rbf + (size_t)b * (NOBJ * NOBJ * ND);
        f32x4 acc = {0.f, 0.f, 0.f, 0.f};
#pragma unroll
        for (int s = 0; s < 5; ++s) {
            const bf16x8 a = *(const bf16x8*)(Rb + ro[s] + d0);   // 16B, L1/L2-resident
            acc = __builtin_amdgcn_mfma_f32_16x16x32_bf16(a, wf[s], acc, 0, 0, 0);
        }
        // C[row=quad*4+r][col=l15] -> out[b][gw+quad*4+r][f=l15]
#pragma unroll
        for (int r = 0; r < 4; ++r) {
            const int gg = gbase + r;
            if (gg < NG) out[((size_t)b * NG + gg) * NF + l15] = acc[r];
        }
    }
}

extern "C" void kernel_launch(void* const* d_in, const int* in_sizes, int n_in,
                              void* d_out, int out_size, void* d_ws, size_t ws_size,
                              hipStream_t stream) {
    const float* R  = (const float*)d_in[0];
    const float* Fw = (const float*)d_in[1];
    if (n_in >= 2 && in_sizes[0] == NF * 9 * ND) { R = (const float*)d_in[1]; Fw = (const float*)d_in[0]; }
    float* out = (float*)d_out;

    unsigned short* Rbf  = (unsigned short*)d_ws;                       // 1 MB
    unsigned short* Wpad = (unsigned short*)((char*)d_ws + RELEMS * 2); // 5 KB

    rgc_pre<<<dim3(257, 1), dim3(256, 1, 1), 0, stream>>>(R, Fw, Rbf, Wpad);
    dim3 grid((NG + 63) / 64, 16);   // 78 x 16 blocks, 2 batches per block
    rgc_main<<<grid, dim3(256, 1, 1), 0, stream>>>(Rbf, Wpad, out);
}